// Round 8
// baseline (145.634 us; speedup 1.0000x reference)
//
#include <hip/hip_runtime.h>
#include <cstdint>

// =====================================================================
// MultiHeadAttention_84576495993495  (round 8)
//
// Algebraic collapse: einsum('bhqk,bhvo->bhvo', attn, v) sums attn over
// BOTH q and k; softmax rows sum to 1 -> factor is exactly S=2048.
//   final = x @ (2048*Wp@Wv)^T + (2048*Wp@bv + bp)
// Wq/bq/Wk/bk unused.
//
// R8 changes (R7 = 140.7us best; gemm1 path had 7.5us + 32MB of split-K
// partial traffic):
//   - gemm1 DIRECT: grid 8x8=64 blocks, 8 BK=128 iters, epilogue writes
//     bf16 * 2048 straight to m2b. k_reduce and the 16MB partial slab
//     are gone (one fewer launch, -30MB traffic).
//   - gemm2 and prep identical to R7 (proven: BK=128 amortizes the
//     vmcnt(0) barrier drain; XCD-grouped panels for A L2 residency).
// =====================================================================

typedef unsigned short u16;
typedef __bf16 bf16x8 __attribute__((ext_vector_type(8)));
typedef float f32x4 __attribute__((ext_vector_type(4)));

__device__ __forceinline__ u16 f2bf(float f) {
  // round-to-nearest-even f32 -> bf16 bits (finite inputs)
  unsigned int u = __float_as_uint(f);
  u += 0x7fffu + ((u >> 16) & 1u);
  return (u16)(u >> 16);
}

// async global->LDS 16B copy; LDS dest = wave-uniform base + lane*16
__device__ __forceinline__ void load16(const void* g, void* l) {
  auto gp = (const __attribute__((address_space(1))) unsigned int*)(uintptr_t)g;
  auto lp = (__attribute__((address_space(3))) unsigned int*)(unsigned int)(uintptr_t)l;
  __builtin_amdgcn_global_load_lds(gp, lp, 16, 0, 0);
}

// ---------------------------------------------------------------------
// Fused prep. Block ranges:
//   [0,8192)      conv x   f32->bf16 (4 elem/thread)
//   [8192,9216)   conv Wp  f32->bf16
//   [9216,10240)  transpose+conv Wv -> Wv^T bf16 (32x32 tiles)
//   [10240,10496) cv[n] = 2048*dot(Wp[n,:],bv) + bp[n]
__global__ void k_prep(const float* __restrict__ x, const float* __restrict__ Wv,
                       const float* __restrict__ bv, const float* __restrict__ Wp,
                       const float* __restrict__ bp, u16* __restrict__ xb,
                       u16* __restrict__ wpb, u16* __restrict__ wvtb,
                       float* __restrict__ cv) {
  __shared__ float tile[32][33];
  const int b = blockIdx.x;
  const int tid = threadIdx.x;
  if (b < 9216) {  // conversions
    const float* src = (b < 8192) ? x : Wp;
    u16* dst = (b < 8192) ? xb : wpb;
    const long base = (long)((b < 8192) ? b : (b - 8192)) * 1024 + tid * 4;
    const float4 v = *(const float4*)(src + base);
    ushort4 o;
    o.x = f2bf(v.x); o.y = f2bf(v.y); o.z = f2bf(v.z); o.w = f2bf(v.w);
    *(ushort4*)(dst + base) = o;
  } else if (b < 10240) {  // transpose Wv
    const int tb = b - 9216;
    const int bi = (tb & 31) * 32;   // output row block (i)
    const int bj = (tb >> 5) * 32;   // output col block (j) = src row block
    const int tx = tid & 31;
    const int ty = tid >> 5;  // 0..7
    for (int r = ty; r < 32; r += 8)
      tile[r][tx] = Wv[(long)(bj + r) * 1024 + bi + tx];
    __syncthreads();
    for (int r = ty; r < 32; r += 8)
      wvtb[(long)(bi + r) * 1024 + bj + tx] = f2bf(tile[tx][r]);
  } else {  // bias fold
    const int row = (b - 10240) * 4 + (tid >> 6);
    const int lane = tid & 63;
    const float* w = Wp + (long)row * 1024;
    float s = 0.f;
    for (int j = lane; j < 1024; j += 64) s += w[j] * bv[j];
    for (int off = 32; off; off >>= 1) s += __shfl_down(s, off, 64);
    if (lane == 0) cv[row] = 2048.f * s + bp[row];
  }
}

// ---------------------------------------------------------------------
// NT bf16 GEMM: BM=128, BN=128, BK=128. 256 threads = 4 waves (2x2),
// each 64x64 (4x4 MFMA acc). 64 MFMA/wave per K-iter (307 cyc) per one
// vmcnt(0) barrier drain -- the amortization that fixed R5/R6.
// LDS XOR-swizzled: 16B chunk kc of row r lives at slot kc ^ (r&7).
// MODE 0: fp32 out + bias, XCD-grouped 1-D grid (gemm2).
// MODE 2: bf16 out * 2048, plain 2-D grid (gemm1 direct).
template <int MODE>
__global__ __launch_bounds__(256, 2) void k_gemm(
    const u16* __restrict__ A, const u16* __restrict__ B, void* __restrict__ Out,
    const float* __restrict__ bias, int M, int N, int K) {
  __shared__ u16 As[128 * 128];  // 32 KB
  __shared__ u16 Bs[128 * 128];  // 32 KB

  const int tid = threadIdx.x;
  const int lane = tid & 63;
  const int wv = tid >> 6;
  const int waveM = (wv & 1) << 6;
  const int waveN = (wv >> 1) << 6;
  const int l15 = lane & 15;
  const int quad = lane >> 4;

  long bm, bn;
  if constexpr (MODE == 0) {
    // XCD grouping: xcd = id&7 owns contiguous m-panels; a panel's
    // (N/128) n-blocks are temporally adjacent on that XCD.
    const int id = blockIdx.x;            // gridDim.x = (M/128)*(N/128)
    const int xcd = id & 7;
    const int j = id >> 3;
    const int nb = N >> 7;
    const int mPerXcd = M / 128 / 8;
    bm = (long)(xcd * mPerXcd + j / nb) * 128;
    bn = (long)(j % nb) * 128;
  } else {
    bm = (long)blockIdx.x * 128;
    bn = (long)blockIdx.y * 128;
  }

  // Staging: 8 load16 calls each for A and B. Call r of wave wv fills
  // LDS rows [r*16 + wv*4, +4). Lane l: row_local = l>>4, slot s=l&15,
  // fetches global chunk kc = s ^ (row&7)   (row&7 == rr&7).
  const int rr = (wv << 2) + (lane >> 4);   // 0..15
  const int s15 = lane & 15;
  const int kc = s15 ^ (rr & 7);
  const u16* Ag = A + (bm + rr) * (long)K + kc * 8;
  const u16* Bg = B + (bn + rr) * (long)K + kc * 8;
  u16* Asw = As + (wv << 9);
  u16* Bsw = Bs + (wv << 9);

  const f32x4 zero = {0.f, 0.f, 0.f, 0.f};
  f32x4 acc[4][4];
#pragma unroll
  for (int i = 0; i < 4; ++i)
#pragma unroll
    for (int j = 0; j < 4; ++j) acc[i][j] = zero;

  for (int k0 = 0; k0 < K; k0 += 128) {
    __syncthreads();  // previous tile fully consumed
#pragma unroll
    for (int r = 0; r < 8; ++r)
      load16(Ag + (long)(r * 16) * K + k0, Asw + r * 2048);
#pragma unroll
    for (int r = 0; r < 8; ++r)
      load16(Bg + (long)(r * 16) * K + k0, Bsw + r * 2048);
    __syncthreads();  // staging drained (vmcnt(0) before s_barrier)

#pragma unroll
    for (int kk = 0; kk < 4; ++kk) {
      const int swz = ((kk << 2) + quad) ^ (l15 & 7);   // swizzled chunk
      bf16x8 af[4], bg[4];
#pragma unroll
      for (int t = 0; t < 4; ++t) {
        af[t] = *(const bf16x8*)(As + (waveM + t * 16 + l15) * 128 + swz * 8);
        bg[t] = *(const bf16x8*)(Bs + (waveN + t * 16 + l15) * 128 + swz * 8);
      }
#pragma unroll
      for (int i = 0; i < 4; ++i)
#pragma unroll
        for (int j = 0; j < 4; ++j)
          acc[i][j] = __builtin_amdgcn_mfma_f32_16x16x32_bf16(af[i], bg[j], acc[i][j], 0, 0, 0);
    }
  }

  // epilogue: C/D layout col = lane&15, row = quad*4 + reg  [m89/m91]
#pragma unroll
  for (int i = 0; i < 4; ++i) {
    const long gm = bm + waveM + i * 16 + quad * 4;
#pragma unroll
    for (int j = 0; j < 4; ++j) {
      const long gn = bn + waveN + j * 16 + l15;
      if constexpr (MODE == 0) {
        const float bb = bias[gn];
#pragma unroll
        for (int r = 0; r < 4; ++r)
          ((float*)Out)[(gm + r) * N + gn] = acc[i][j][r] + bb;
      } else {
#pragma unroll
        for (int r = 0; r < 4; ++r)
          ((u16*)Out)[(gm + r) * N + gn] = f2bf(acc[i][j][r] * 2048.f);
      }
    }
  }
}

// =====================================================================
extern "C" void kernel_launch(void* const* d_in, const int* in_sizes, int n_in,
                              void* d_out, int out_size, void* d_ws, size_t ws_size,
                              hipStream_t stream) {
  // setup_inputs order: x, Wq, bq, Wk, bk, Wv, bv, Wp, bp
  const float* x  = (const float*)d_in[0];
  const float* Wv = (const float*)d_in[5];
  const float* bv = (const float*)d_in[6];
  const float* Wp = (const float*)d_in[7];
  const float* bp = (const float*)d_in[8];

  char* ws = (char*)d_ws;
  u16* xb    = (u16*)(ws);                      // 16 MB  x bf16
  u16* wpb   = (u16*)(ws + (16u << 20));        //  2 MB  Wp bf16
  u16* wvtb  = (u16*)(ws + (18u << 20));        //  2 MB  Wv^T bf16
  u16* m2b   = (u16*)(ws + (20u << 20));        //  2 MB  M2 bf16
  float* cv  = (float*)(ws + (22u << 20));      //  4 KB  folded bias

  // 1) fused prep: conv x / conv Wp / transpose Wv / bias fold
  k_prep<<<10496, 256, 0, stream>>>(x, Wv, bv, Wp, bp, xb, wpb, wvtb, cv);

  // 2) M2 = bf16(2048 * Wp @ Wv)  -- direct, 64 blocks x 8 iters
  k_gemm<2><<<dim3(8, 8), 256, 0, stream>>>(wpb, wvtb, m2b, nullptr,
                                            1024, 1024, 1024);

  // 3) out = x @ M2^T + cv  (64 panels x 8 n-blocks = 512, XCD-grouped)
  k_gemm<0><<<512, 256, 0, stream>>>(xb, m2b, d_out, cv,
                                     8192, 1024, 1024);
}

// Round 9
// 142.047 us; speedup vs baseline: 1.0252x; 1.0252x over previous
//
#include <hip/hip_runtime.h>
#include <cstdint>

// =====================================================================
// MultiHeadAttention_84576495993495  (round 9 = R7 revert + split-K=2)
//
// Algebraic collapse: einsum('bhqk,bhvo->bhvo', attn, v) sums attn over
// BOTH q and k; softmax rows sum to 1 -> factor is exactly S=2048.
//   final = x @ (2048*Wp@Wv)^T + (2048*Wp@bv + bp)
// Wq/bq/Wk/bk unused.
//
// R9: R8's direct gemm1 (64 latency-serial blocks) regressed +5us ->
// revert to R7 (140.7us best). Single change vs R7: gemm1 split-K 4->2
// (128 blocks x 4 iters; halves partial-slab traffic 32->16MB).
// Proven pieces kept untouched:
//   - BK=128 BM=BN=128 GEMM: 64 MFMA/wave/iter amortizes the vmcnt(0)
//     barrier drain (this fixed the R5/R6 MfmaUtil=12% latency wall).
//   - XCD-grouped gemm2 dispatch (A-panel L2-resident per XCD).
//   - Fused prep (conv x / conv Wp / transpose Wv / bias fold).
// Lesson R5/R6/R8: every kernel here is latency-dominated; never trade
// parallelism for bytes.
// =====================================================================

typedef unsigned short u16;
typedef __bf16 bf16x8 __attribute__((ext_vector_type(8)));
typedef float f32x4 __attribute__((ext_vector_type(4)));

__device__ __forceinline__ u16 f2bf(float f) {
  // round-to-nearest-even f32 -> bf16 bits (finite inputs)
  unsigned int u = __float_as_uint(f);
  u += 0x7fffu + ((u >> 16) & 1u);
  return (u16)(u >> 16);
}

// async global->LDS 16B copy; LDS dest = wave-uniform base + lane*16
__device__ __forceinline__ void load16(const void* g, void* l) {
  auto gp = (const __attribute__((address_space(1))) unsigned int*)(uintptr_t)g;
  auto lp = (__attribute__((address_space(3))) unsigned int*)(unsigned int)(uintptr_t)l;
  __builtin_amdgcn_global_load_lds(gp, lp, 16, 0, 0);
}

// ---------------------------------------------------------------------
// Fused prep. Block ranges:
//   [0,8192)      conv x   f32->bf16 (4 elem/thread)
//   [8192,9216)   conv Wp  f32->bf16
//   [9216,10240)  transpose+conv Wv -> Wv^T bf16 (32x32 tiles)
//   [10240,10496) cv[n] = 2048*dot(Wp[n,:],bv) + bp[n]
__global__ void k_prep(const float* __restrict__ x, const float* __restrict__ Wv,
                       const float* __restrict__ bv, const float* __restrict__ Wp,
                       const float* __restrict__ bp, u16* __restrict__ xb,
                       u16* __restrict__ wpb, u16* __restrict__ wvtb,
                       float* __restrict__ cv) {
  __shared__ float tile[32][33];
  const int b = blockIdx.x;
  const int tid = threadIdx.x;
  if (b < 9216) {  // conversions
    const float* src = (b < 8192) ? x : Wp;
    u16* dst = (b < 8192) ? xb : wpb;
    const long base = (long)((b < 8192) ? b : (b - 8192)) * 1024 + tid * 4;
    const float4 v = *(const float4*)(src + base);
    ushort4 o;
    o.x = f2bf(v.x); o.y = f2bf(v.y); o.z = f2bf(v.z); o.w = f2bf(v.w);
    *(ushort4*)(dst + base) = o;
  } else if (b < 10240) {  // transpose Wv
    const int tb = b - 9216;
    const int bi = (tb & 31) * 32;   // output row block (i)
    const int bj = (tb >> 5) * 32;   // output col block (j) = src row block
    const int tx = tid & 31;
    const int ty = tid >> 5;  // 0..7
    for (int r = ty; r < 32; r += 8)
      tile[r][tx] = Wv[(long)(bj + r) * 1024 + bi + tx];
    __syncthreads();
    for (int r = ty; r < 32; r += 8)
      wvtb[(long)(bi + r) * 1024 + bj + tx] = f2bf(tile[tx][r]);
  } else {  // bias fold
    const int row = (b - 10240) * 4 + (tid >> 6);
    const int lane = tid & 63;
    const float* w = Wp + (long)row * 1024;
    float s = 0.f;
    for (int j = lane; j < 1024; j += 64) s += w[j] * bv[j];
    for (int off = 32; off; off >>= 1) s += __shfl_down(s, off, 64);
    if (lane == 0) cv[row] = 2048.f * s + bp[row];
  }
}

// ---------------------------------------------------------------------
// reduce 2 split-K fp32 partial slabs -> bf16, *2048
__global__ void k_reduce(const float* __restrict__ p, u16* __restrict__ dst) {
  const long i = (long)(blockIdx.x * 256 + threadIdx.x) * 4;
  const float4 a = *(const float4*)(p + i);
  const float4 b = *(const float4*)(p + 1048576 + i);
  ushort4 o;
  o.x = f2bf((a.x + b.x) * 2048.f);
  o.y = f2bf((a.y + b.y) * 2048.f);
  o.z = f2bf((a.z + b.z) * 2048.f);
  o.w = f2bf((a.w + b.w) * 2048.f);
  *(ushort4*)(dst + i) = o;
}

// ---------------------------------------------------------------------
// NT bf16 GEMM: Out[M,N] (+bias) = A[M,K] @ B[N,K]^T
// BM=128, BN=128, BK=128. 256 threads = 4 waves (2x2), each 64x64
// (4x4 MFMA acc). Per K-iter: 64 MFMA/wave (307 cyc) per one vmcnt(0)
// drain -- amortizes the barrier-drain latency that capped R5/R6.
// LDS XOR-swizzled: 16B chunk kc of row r lives at slot kc ^ (r&7).
// MODE 0: fp32 out + bias, XCD-grouped 1-D grid. MODE 1: split-K slab.
template <int MODE>
__global__ __launch_bounds__(256, 2) void k_gemm(
    const u16* __restrict__ A, const u16* __restrict__ B, float* __restrict__ Out,
    const float* __restrict__ bias, int M, int N, int K) {
  __shared__ u16 As[128 * 128];  // 32 KB
  __shared__ u16 Bs[128 * 128];  // 32 KB

  const int tid = threadIdx.x;
  const int lane = tid & 63;
  const int wv = tid >> 6;
  const int waveM = (wv & 1) << 6;
  const int waveN = (wv >> 1) << 6;
  const int l15 = lane & 15;
  const int quad = lane >> 4;

  long bm, bn;
  int kBeg, kEnd;
  if constexpr (MODE == 0) {
    // XCD grouping: xcd = id&7 owns contiguous m-panels; a panel's
    // (N/128) n-blocks are temporally adjacent on that XCD.
    const int id = blockIdx.x;            // gridDim.x = (M/128)*(N/128)
    const int xcd = id & 7;
    const int j = id >> 3;
    const int nb = N >> 7;
    const int mPerXcd = M / 128 / 8;
    bm = (long)(xcd * mPerXcd + j / nb) * 128;
    bn = (long)(j % nb) * 128;
    kBeg = 0; kEnd = K;
  } else {
    bm = (long)blockIdx.x * 128;
    bn = (long)blockIdx.y * 128;
    const int kChunk = K / gridDim.z;
    kBeg = blockIdx.z * kChunk;
    kEnd = kBeg + kChunk;
  }

  // Staging: 8 load16 calls each for A and B. Call r of wave wv fills
  // LDS rows [r*16 + wv*4, +4). Lane l: row_local = l>>4, slot s=l&15,
  // fetches global chunk kc = s ^ (row&7)   (row&7 == rr&7).
  const int rr = (wv << 2) + (lane >> 4);   // 0..15
  const int s15 = lane & 15;
  const int kc = s15 ^ (rr & 7);
  const u16* Ag = A + (bm + rr) * (long)K + kc * 8;
  const u16* Bg = B + (bn + rr) * (long)K + kc * 8;
  u16* Asw = As + (wv << 9);
  u16* Bsw = Bs + (wv << 9);

  const f32x4 zero = {0.f, 0.f, 0.f, 0.f};
  f32x4 acc[4][4];
#pragma unroll
  for (int i = 0; i < 4; ++i)
#pragma unroll
    for (int j = 0; j < 4; ++j) acc[i][j] = zero;

  for (int k0 = kBeg; k0 < kEnd; k0 += 128) {
    __syncthreads();  // previous tile fully consumed
#pragma unroll
    for (int r = 0; r < 8; ++r)
      load16(Ag + (long)(r * 16) * K + k0, Asw + r * 2048);
#pragma unroll
    for (int r = 0; r < 8; ++r)
      load16(Bg + (long)(r * 16) * K + k0, Bsw + r * 2048);
    __syncthreads();  // staging drained (vmcnt(0) before s_barrier)

#pragma unroll
    for (int kk = 0; kk < 4; ++kk) {
      const int swz = ((kk << 2) + quad) ^ (l15 & 7);   // swizzled chunk
      bf16x8 af[4], bg[4];
#pragma unroll
      for (int t = 0; t < 4; ++t) {
        af[t] = *(const bf16x8*)(As + (waveM + t * 16 + l15) * 128 + swz * 8);
        bg[t] = *(const bf16x8*)(Bs + (waveN + t * 16 + l15) * 128 + swz * 8);
      }
#pragma unroll
      for (int i = 0; i < 4; ++i)
#pragma unroll
        for (int j = 0; j < 4; ++j)
          acc[i][j] = __builtin_amdgcn_mfma_f32_16x16x32_bf16(af[i], bg[j], acc[i][j], 0, 0, 0);
    }
  }

  // epilogue: C/D layout col = lane&15, row = quad*4 + reg  [m89/m91]
  float* outp = (MODE == 1) ? Out + (long)blockIdx.z * M * N : Out;
#pragma unroll
  for (int i = 0; i < 4; ++i) {
    const long gm = bm + waveM + i * 16 + quad * 4;
#pragma unroll
    for (int j = 0; j < 4; ++j) {
      const long gn = bn + waveN + j * 16 + l15;
      const float bb = (MODE == 0) ? bias[gn] : 0.f;
#pragma unroll
      for (int r = 0; r < 4; ++r)
        outp[(gm + r) * N + gn] = acc[i][j][r] + bb;
    }
  }
}

// =====================================================================
extern "C" void kernel_launch(void* const* d_in, const int* in_sizes, int n_in,
                              void* d_out, int out_size, void* d_ws, size_t ws_size,
                              hipStream_t stream) {
  // setup_inputs order: x, Wq, bq, Wk, bk, Wv, bv, Wp, bp
  const float* x  = (const float*)d_in[0];
  const float* Wv = (const float*)d_in[5];
  const float* bv = (const float*)d_in[6];
  const float* Wp = (const float*)d_in[7];
  const float* bp = (const float*)d_in[8];

  char* ws = (char*)d_ws;
  u16* xb    = (u16*)(ws);                      // 16 MB  x bf16
  u16* wpb   = (u16*)(ws + (16u << 20));        //  2 MB  Wp bf16
  u16* wvtb  = (u16*)(ws + (18u << 20));        //  2 MB  Wv^T bf16
  u16* m2b   = (u16*)(ws + (20u << 20));        //  2 MB  M2 bf16
  float* cv  = (float*)(ws + (22u << 20));      //  4 KB  folded bias
  float* m2f = (float*)(ws + (22u << 20) + 4096);  // 8 MB split-K partials

  // 1) fused prep: conv x / conv Wp / transpose Wv / bias fold
  k_prep<<<10496, 256, 0, stream>>>(x, Wv, bv, Wp, bp, xb, wpb, wvtb, cv);

  // 2) M2 partials = Wp @ Wv  (split-K=2: 8x8x2 = 128 blocks, 4 iters each)
  k_gemm<1><<<dim3(8, 8, 2), 256, 0, stream>>>(wpb, wvtb, m2f, nullptr,
                                               1024, 1024, 1024);
  // 3) M2 = bf16(2048 * sum of partials)
  k_reduce<<<1024, 256, 0, stream>>>(m2f, m2b);

  // 4) out = x @ M2^T + cv  (64 panels x 8 n-blocks = 512, XCD-grouped)
  k_gemm<0><<<512, 256, 0, stream>>>(xb, m2b, (float*)d_out, cv,
                                     8192, 1024, 1024);
}